// Round 4
// baseline (831.149 us; speedup 1.0000x reference)
//
#include <hip/hip_runtime.h>

// Per-point expert-indexed MLP: h = LeakyReLU(h @ W[idx] + b[idx]) x3.
// Counting-sort points by expert (segments padded to 1024) so each mlp block
// is expert-uniform; weights staged once per block in LDS (4.8 KB, wave-
// broadcast reads). MPT=4 points/thread so each ds_read_b128 weight fragment
// feeds 16 FMAs (LDS-pipe demand ~11us).
//
// R3 LESSON: unfused MPT=4 needs ~220 live VGPRs -> scratch spill (1.1 GB HBM
// traffic, 485us). Fix: FUSE layers 1+2 — compute h1 in chunks of 4 and
// accumulate into h2 immediately. Peak live = h0[16]+h2[16]+t[4] = 36/point,
// ~170 VGPRs total at MPT=4 -> fits under the 256-VGPR cap, no spill.
//
// 3 dispatches: k_hist -> k_scatter (scan fused, stages sorted x rows) -> k_mlp.

#define L_EXP 16
#define IN0   7
#define C0    16
#define C1    32
#define C2    16
#define NEG   0.2f
#define BLK   256
#define HBLK  64
#define MPT   4              // points per thread in k_mlp
#define SEGPAD (BLK * MPT)   // 1024: per-expert segment padding

// ws layout (int32):
//   [0..15]    counts per expert        (published by k_scatter block 0)
//   [16..32]   padded seg offsets, [32]=padded total (published by block 0)
//   [48..63]   scatter cursors          (zeroed by k_hist block 0)
//   [64..1087] partial histograms (HBLK x 16, from k_hist)
//   float idx 4096.. : staged rows, 8 floats/slot: x[0..6], as_float(point id)
#define WS_CUR   48
#define WS_PART  64
#define WS_STAGE 4096

__global__ void k_hist(const int* __restrict__ idx, int n, int* __restrict__ ws) {
    __shared__ int bins[L_EXP];
    int t = threadIdx.x;
    if (t < L_EXP) bins[t] = 0;
    __syncthreads();
    for (int i = blockIdx.x * blockDim.x + t; i < n; i += gridDim.x * blockDim.x)
        atomicAdd(&bins[idx[i] & 15], 1);
    __syncthreads();
    if (t < L_EXP) {
        ws[WS_PART + blockIdx.x * L_EXP + t] = bins[t];
        if (blockIdx.x == 0) ws[WS_CUR + t] = 0;  // zero cursors for k_scatter
    }
}

__global__ void k_scatter(const int* __restrict__ idx, const float* __restrict__ x,
                          int n, int* __restrict__ ws, float* __restrict__ stage) {
    __shared__ int scnt[L_EXP];
    __shared__ int soff[L_EXP + 1];
    __shared__ int lcount[L_EXP];
    __shared__ int gbase[L_EXP];
    int t = threadIdx.x;
    if (t < L_EXP) {
        int s = 0;
        for (int b = 0; b < HBLK; ++b) s += ws[WS_PART + b * L_EXP + t];
        scnt[t] = s;
        lcount[t] = 0;
    }
    __syncthreads();
    if (t == 0) {
        int run = 0;
        for (int e = 0; e < L_EXP; ++e) {
            soff[e] = run;
            run += ((scnt[e] + SEGPAD - 1) / SEGPAD) * SEGPAD;
        }
        soff[L_EXP] = run;
        if (blockIdx.x == 0) {  // publish meta for k_mlp
            for (int e = 0; e < L_EXP; ++e) {
                ws[e] = scnt[e];
                ws[16 + e] = soff[e];
            }
            ws[32] = run;
        }
    }
    int i = blockIdx.x * BLK + t;
    bool act = (i < n);
    int e = 0, r = 0;
    float xv[IN0];
    if (act) {
        e = idx[i] & 15;
#pragma unroll
        for (int c = 0; c < IN0; ++c) xv[c] = x[i * IN0 + c];
        r = atomicAdd(&lcount[e], 1);
    }
    __syncthreads();
    if (t < L_EXP) gbase[t] = atomicAdd(&ws[WS_CUR + t], lcount[t]);
    __syncthreads();
    if (act) {
        int pos = soff[e] + gbase[e] + r;
        float4* sp = reinterpret_cast<float4*>(stage + (size_t)pos * 8);
        sp[0] = make_float4(xv[0], xv[1], xv[2], xv[3]);
        sp[1] = make_float4(xv[4], xv[5], xv[6], __int_as_float(i));
    }
}

__device__ __forceinline__ float leaky(float a) { return fmaxf(a, NEG * a); }

__device__ __forceinline__ float4 f4_fma(float s, float4 w, float4 a) {
    a.x = fmaf(s, w.x, a.x);
    a.y = fmaf(s, w.y, a.y);
    a.z = fmaf(s, w.z, a.z);
    a.w = fmaf(s, w.w, a.w);
    return a;
}

__device__ __forceinline__ float4 f4_leaky(float4 a) {
    a.x = fmaxf(a.x, NEG * a.x);
    a.y = fmaxf(a.y, NEG * a.y);
    a.z = fmaxf(a.z, NEG * a.z);
    a.w = fmaxf(a.w, NEG * a.w);
    return a;
}

__global__ void __launch_bounds__(BLK, 2) k_mlp(
    const int* __restrict__ meta, const float* __restrict__ stage,
    const float* __restrict__ W0, const float* __restrict__ b0,
    const float* __restrict__ W1, const float* __restrict__ b1,
    const float* __restrict__ W2, const float* __restrict__ b2,
    float* __restrict__ out) {
    __shared__ __align__(16) float sW0[IN0 * C0];  // [c][o] row-major
    __shared__ __align__(16) float sB0[C0];
    __shared__ __align__(16) float sW1[C0 * C1];
    __shared__ __align__(16) float sB1[C1];
    __shared__ __align__(16) float sW2[C1 * C2];
    __shared__ __align__(16) float sB2[C2];

    int start = blockIdx.x * SEGPAD;
    if (start >= meta[32]) return;

    int e = 0;
    while (start >= meta[16 + e + 1]) ++e;
    e = __builtin_amdgcn_readfirstlane(e);

    int t = threadIdx.x;
    {
        const float* w0p = W0 + e * (IN0 * C0);
        const float* w1p = W1 + e * (C0 * C1);
        const float* w2p = W2 + e * (C1 * C2);
        if (t < IN0 * C0) sW0[t] = w0p[t];
        if (t >= 128 && t < 128 + C0) sB0[t - 128] = b0[e * C0 + (t - 128)];
        if (t >= 160 && t < 160 + C1) sB1[t - 160] = b1[e * C1 + (t - 160)];
        if (t >= 192 && t < 192 + C2) sB2[t - 192] = b2[e * C2 + (t - 192)];
        for (int k = t; k < C0 * C1; k += BLK) sW1[k] = w1p[k];
        for (int k = t; k < C1 * C2; k += BLK) sW2[k] = w2p[k];
    }
    __syncthreads();

    int seg = meta[16 + e];
    int cnt = meta[e];
    int j0 = start - seg + t;

    // load MPT staged rows (coalesced 32B/lane); pad slots hold harmless poison
    float xv[MPT][IN0];
    int   pid[MPT];
    bool  act[MPT];
#pragma unroll
    for (int m = 0; m < MPT; ++m) {
        int j = j0 + m * BLK;
        act[m] = (j < cnt);
        const float4* sp = reinterpret_cast<const float4*>(stage + (size_t)(seg + j) * 8);
        float4 a = sp[0];
        float4 b = sp[1];
        xv[m][0] = a.x; xv[m][1] = a.y; xv[m][2] = a.z; xv[m][3] = a.w;
        xv[m][4] = b.x; xv[m][5] = b.y; xv[m][6] = b.z;
        pid[m] = __float_as_int(b.w);
    }

    // ---- Layer 0: 7 -> 16 ----
    float h0[MPT][C0];
#pragma unroll
    for (int og = 0; og < C0 / 4; ++og) {
        float4 bb = *reinterpret_cast<const float4*>(&sB0[og * 4]);
        float4 acc[MPT];
#pragma unroll
        for (int m = 0; m < MPT; ++m) acc[m] = bb;
#pragma unroll
        for (int c = 0; c < IN0; ++c) {
            float4 w = *reinterpret_cast<const float4*>(&sW0[c * C0 + og * 4]);
#pragma unroll
            for (int m = 0; m < MPT; ++m) acc[m] = f4_fma(xv[m][c], w, acc[m]);
        }
#pragma unroll
        for (int m = 0; m < MPT; ++m) {
            acc[m] = f4_leaky(acc[m]);
            h0[m][og * 4 + 0] = acc[m].x; h0[m][og * 4 + 1] = acc[m].y;
            h0[m][og * 4 + 2] = acc[m].z; h0[m][og * 4 + 3] = acc[m].w;
        }
    }

    // ---- Layers 1+2 fused: h1 in chunks of 4, accumulate h2 immediately ----
    // Live per point: h0[16] + h2[16] + t[4] = 36 regs -> no spill at MPT=4.
    float4 h2[MPT][C2 / 4];
    {
        float4 b2v0 = *reinterpret_cast<const float4*>(&sB2[0]);
        float4 b2v1 = *reinterpret_cast<const float4*>(&sB2[4]);
        float4 b2v2 = *reinterpret_cast<const float4*>(&sB2[8]);
        float4 b2v3 = *reinterpret_cast<const float4*>(&sB2[12]);
#pragma unroll
        for (int m = 0; m < MPT; ++m) {
            h2[m][0] = b2v0; h2[m][1] = b2v1; h2[m][2] = b2v2; h2[m][3] = b2v3;
        }
    }
#pragma unroll
    for (int ch = 0; ch < C1 / 4; ++ch) {   // h1 neurons ch*4 .. ch*4+3
        float4 tv[MPT];
        float4 bb = *reinterpret_cast<const float4*>(&sB1[ch * 4]);
#pragma unroll
        for (int m = 0; m < MPT; ++m) tv[m] = bb;
#pragma unroll
        for (int c = 0; c < C0; ++c) {
            float4 w = *reinterpret_cast<const float4*>(&sW1[c * C1 + ch * 4]);
#pragma unroll
            for (int m = 0; m < MPT; ++m) tv[m] = f4_fma(h0[m][c], w, tv[m]);
        }
#pragma unroll
        for (int m = 0; m < MPT; ++m) tv[m] = f4_leaky(tv[m]);
        // accumulate into h2: h2[o] += t[q] * W2[ch*4+q][o]
#pragma unroll
        for (int q = 0; q < 4; ++q) {
            int c1 = ch * 4 + q;
#pragma unroll
            for (int og = 0; og < C2 / 4; ++og) {
                float4 w = *reinterpret_cast<const float4*>(&sW2[c1 * C2 + og * 4]);
#pragma unroll
                for (int m = 0; m < MPT; ++m) {
                    float s = (q == 0) ? tv[m].x : (q == 1) ? tv[m].y
                                       : (q == 2) ? tv[m].z : tv[m].w;
                    h2[m][og] = f4_fma(s, w, h2[m][og]);
                }
            }
        }
    }

    // ---- store ----
#pragma unroll
    for (int m = 0; m < MPT; ++m) {
        if (act[m]) {
            float4* outp = reinterpret_cast<float4*>(out + (size_t)pid[m] * C2);
#pragma unroll
            for (int og = 0; og < C2 / 4; ++og) outp[og] = f4_leaky(h2[m][og]);
        }
    }
}

extern "C" void kernel_launch(void* const* d_in, const int* in_sizes, int n_in,
                              void* d_out, int out_size, void* d_ws, size_t ws_size,
                              hipStream_t stream) {
    const float* x  = (const float*)d_in[0];
    const int*  idx = (const int*)d_in[1];
    const float* W0 = (const float*)d_in[2];
    const float* b0 = (const float*)d_in[3];
    const float* W1 = (const float*)d_in[4];
    const float* b1 = (const float*)d_in[5];
    const float* W2 = (const float*)d_in[6];
    const float* b2 = (const float*)d_in[7];
    float* out = (float*)d_out;

    int n = in_sizes[1];  // N
    int* ws = (int*)d_ws;
    float* stage = (float*)d_ws + WS_STAGE;

    k_hist<<<HBLK, BLK, 0, stream>>>(idx, n, ws);

    int nblk = (n + BLK - 1) / BLK;
    k_scatter<<<nblk, BLK, 0, stream>>>(idx, x, n, ws, stage);

    // padded total <= n + 16*(SEGPAD-1)
    int mblk = (n + L_EXP * (SEGPAD - 1) + SEGPAD - 1) / SEGPAD;
    k_mlp<<<mblk, BLK, 0, stream>>>(ws, stage, W0, b0, W1, b1, W2, b2, out);
}

// Round 5
// 147.848 us; speedup vs baseline: 5.6216x; 5.6216x over previous
//
#include <hip/hip_runtime.h>

// Per-point expert-indexed MLP: h = LeakyReLU(h @ W[idx] + b[idx]) x3.
// Counting-sort points by expert (segments padded to BLK) so each mlp block is
// expert-uniform. KEY DESIGN (R4 lesson): MPT=1 (no register blocking — MPT=4
// spilled 1+ GB of scratch twice), zero LDS, and ZERO DIVERGENT CONTROL FLOW
// before the weight reads so the compiler can select s_load (scalar cache)
// for all 1200 uniform-address weight/bias floats. R2's attempt failed only
// because weight loads sat after a divergent per-lane `return`. Here all math
// is unconditional (padded stage slots are valid poison memory); only the
// final stores are predicated. VALU floor ~7us; SMEM/LDS/VMEM off the
// critical path.
//
// 3 dispatches: k_hist -> k_scatter (scan fused, stages sorted x rows) -> k_mlp.

#define L_EXP 16
#define IN0   7
#define C0    16
#define C1    32
#define C2    16
#define NEG   0.2f
#define BLK   256
#define HBLK  64
#define SEGPAD BLK           // per-expert segment padding

// ws layout (int32):
//   [0..15]    counts per expert        (published by k_scatter block 0)
//   [16..32]   padded seg offsets, [32]=padded total (published by block 0)
//   [48..63]   scatter cursors          (zeroed by k_hist block 0)
//   [64..1087] partial histograms (HBLK x 16, from k_hist)
//   float idx 4096.. : staged rows, 8 floats/slot: x[0..6], as_float(point id)
#define WS_CUR   48
#define WS_PART  64
#define WS_STAGE 4096

__global__ void k_hist(const int* __restrict__ idx, int n, int* __restrict__ ws) {
    __shared__ int bins[L_EXP];
    int t = threadIdx.x;
    if (t < L_EXP) bins[t] = 0;
    __syncthreads();
    for (int i = blockIdx.x * blockDim.x + t; i < n; i += gridDim.x * blockDim.x)
        atomicAdd(&bins[idx[i] & 15], 1);
    __syncthreads();
    if (t < L_EXP) {
        ws[WS_PART + blockIdx.x * L_EXP + t] = bins[t];
        if (blockIdx.x == 0) ws[WS_CUR + t] = 0;  // zero cursors for k_scatter
    }
}

__global__ void k_scatter(const int* __restrict__ idx, const float* __restrict__ x,
                          int n, int* __restrict__ ws, float* __restrict__ stage) {
    __shared__ int scnt[L_EXP];
    __shared__ int soff[L_EXP + 1];
    __shared__ int lcount[L_EXP];
    __shared__ int gbase[L_EXP];
    int t = threadIdx.x;
    if (t < L_EXP) {
        int s = 0;
        for (int b = 0; b < HBLK; ++b) s += ws[WS_PART + b * L_EXP + t];
        scnt[t] = s;
        lcount[t] = 0;
    }
    __syncthreads();
    if (t == 0) {
        int run = 0;
        for (int e = 0; e < L_EXP; ++e) {
            soff[e] = run;
            run += ((scnt[e] + SEGPAD - 1) / SEGPAD) * SEGPAD;
        }
        soff[L_EXP] = run;
        if (blockIdx.x == 0) {  // publish meta for k_mlp
            for (int e = 0; e < L_EXP; ++e) {
                ws[e] = scnt[e];
                ws[16 + e] = soff[e];
            }
            ws[32] = run;
        }
    }
    int i = blockIdx.x * BLK + t;
    bool act = (i < n);
    int e = 0, r = 0;
    float xv[IN0];
    if (act) {
        e = idx[i] & 15;
#pragma unroll
        for (int c = 0; c < IN0; ++c) xv[c] = x[i * IN0 + c];
        r = atomicAdd(&lcount[e], 1);
    }
    __syncthreads();
    if (t < L_EXP) gbase[t] = atomicAdd(&ws[WS_CUR + t], lcount[t]);
    __syncthreads();
    if (act) {
        int pos = soff[e] + gbase[e] + r;
        float4* sp = reinterpret_cast<float4*>(stage + (size_t)pos * 8);
        sp[0] = make_float4(xv[0], xv[1], xv[2], xv[3]);
        sp[1] = make_float4(xv[4], xv[5], xv[6], __int_as_float(i));
    }
}

__device__ __forceinline__ float leaky(float a) { return fmaxf(a, NEG * a); }

__global__ void __launch_bounds__(BLK) k_mlp(
    const int* __restrict__ meta, const float* __restrict__ stage,
    const float* __restrict__ W0, const float* __restrict__ b0,
    const float* __restrict__ W1, const float* __restrict__ b1,
    const float* __restrict__ W2, const float* __restrict__ b2,
    float* __restrict__ out) {
    int start = blockIdx.x * BLK;
    if (start >= meta[32]) return;  // uniform branch only

    // whole block lies in one expert's padded segment (uniform scalar loop)
    int e = 0;
    while (start >= meta[16 + e + 1]) ++e;
    e = __builtin_amdgcn_readfirstlane(e);

    int seg = meta[16 + e];
    int cnt = meta[e];
    int t = threadIdx.x;
    int j = start - seg + t;
    bool act = (j < cnt);  // NO divergent branch until the final store

    // staged row: coalesced 32B/lane; padded slots hold harmless poison
    const float4* sp = reinterpret_cast<const float4*>(stage + (size_t)(seg + j) * 8);
    float4 ra = sp[0];
    float4 rb = sp[1];
    float xv[IN0] = {ra.x, ra.y, ra.z, ra.w, rb.x, rb.y, rb.z};
    int pid = __float_as_int(rb.w);

    // Uniform weight pointers -> s_load (scalar cache) in uniform control flow.
    const float* __restrict__ w0p = W0 + e * (IN0 * C0);
    const float* __restrict__ b0p = b0 + e * C0;
    const float* __restrict__ w1p = W1 + e * (C0 * C1);
    const float* __restrict__ b1p = b1 + e * C1;
    const float* __restrict__ w2p = W2 + e * (C1 * C2);
    const float* __restrict__ b2p = b2 + e * C2;

    // ---- Layer 0: 7 -> 16 ----
    float h0[C0];
#pragma unroll
    for (int o = 0; o < C0; ++o) h0[o] = b0p[o];
#pragma unroll
    for (int c = 0; c < IN0; ++c) {
        float hv = xv[c];
#pragma unroll
        for (int o = 0; o < C0; ++o) h0[o] = fmaf(hv, w0p[c * C0 + o], h0[o]);
    }
#pragma unroll
    for (int o = 0; o < C0; ++o) h0[o] = leaky(h0[o]);

    // ---- Layer 1: 16 -> 32 ----
    float h1[C1];
#pragma unroll
    for (int o = 0; o < C1; ++o) h1[o] = b1p[o];
#pragma unroll
    for (int c = 0; c < C0; ++c) {
        float hv = h0[c];
#pragma unroll
        for (int o = 0; o < C1; ++o) h1[o] = fmaf(hv, w1p[c * C1 + o], h1[o]);
    }
#pragma unroll
    for (int o = 0; o < C1; ++o) h1[o] = leaky(h1[o]);

    // ---- Layer 2: 32 -> 16 ----
    float h2[C2];
#pragma unroll
    for (int o = 0; o < C2; ++o) h2[o] = b2p[o];
#pragma unroll
    for (int c = 0; c < C1; ++c) {
        float hv = h1[c];
#pragma unroll
        for (int o = 0; o < C2; ++o) h2[o] = fmaf(hv, w2p[c * C2 + o], h2[o]);
    }

    // ---- predicated store (the ONLY divergent region) ----
    if (act) {
        float4* outp = reinterpret_cast<float4*>(out + (size_t)pid * C2);
#pragma unroll
        for (int og = 0; og < C2 / 4; ++og) {
            float4 o;
            o.x = leaky(h2[og * 4 + 0]);
            o.y = leaky(h2[og * 4 + 1]);
            o.z = leaky(h2[og * 4 + 2]);
            o.w = leaky(h2[og * 4 + 3]);
            outp[og] = o;
        }
    }
}

extern "C" void kernel_launch(void* const* d_in, const int* in_sizes, int n_in,
                              void* d_out, int out_size, void* d_ws, size_t ws_size,
                              hipStream_t stream) {
    const float* x  = (const float*)d_in[0];
    const int*  idx = (const int*)d_in[1];
    const float* W0 = (const float*)d_in[2];
    const float* b0 = (const float*)d_in[3];
    const float* W1 = (const float*)d_in[4];
    const float* b1 = (const float*)d_in[5];
    const float* W2 = (const float*)d_in[6];
    const float* b2 = (const float*)d_in[7];
    float* out = (float*)d_out;

    int n = in_sizes[1];  // N
    int* ws = (int*)d_ws;
    float* stage = (float*)d_ws + WS_STAGE;

    k_hist<<<HBLK, BLK, 0, stream>>>(idx, n, ws);

    int nblk = (n + BLK - 1) / BLK;
    k_scatter<<<nblk, BLK, 0, stream>>>(idx, x, n, ws, stage);

    // padded total <= n + 16*(SEGPAD-1)
    int mblk = (n + L_EXP * (SEGPAD - 1) + SEGPAD - 1) / SEGPAD;
    k_mlp<<<mblk, BLK, 0, stream>>>(ws, stage, W0, b0, W1, b1, W2, b2, out);
}